// Round 7
// baseline (242.235 us; speedup 1.0000x reference)
//
#include <hip/hip_runtime.h>

#define IN_F 32
#define OUT_F 32
#define EDGE_F 16
#define BN_EPS 1e-5f
#define SLOPE 0.01f
#define NBUCKET 128

typedef _Float16 half_t;
typedef __attribute__((ext_vector_type(4))) _Float16 h4;
typedef __attribute__((ext_vector_type(8))) _Float16 f16x8;
typedef __attribute__((ext_vector_type(4))) float f32x4;

#define BCOLS 576
#define BSTRIDE_B 80

// ---------------- P0: build Bt[col][k] fp16; block 0 zeroes stats+hist ----------------
__global__ __launch_bounds__(256) void prep_bt_kernel(
    const float* __restrict__ W, const float* __restrict__ b,
    const float* __restrict__ root, half_t* __restrict__ BtG,
    float* __restrict__ stats, int* __restrict__ hist) {
  if (blockIdx.x == 0) {
    if (threadIdx.x < 64) stats[threadIdx.x] = 0.f;
    else if (threadIdx.x < 64 + NBUCKET) hist[threadIdx.x - 64] = 0;
  }
  int idx = blockIdx.x * 256 + threadIdx.x;
  if (idx >= BCOLS * 32) return;
  int o = idx & 31;
  int k = (idx >> 5) & 31;
  int fp = idx >> 10;
  float v;
  int col;
  if (fp < 16) {
    v = W[(size_t)fp * 1024 + k * 32 + o];
    col = fp * 32 + o;
  } else if (fp == 16) {
    v = b[k * 32 + o];
    col = 512 + o;
  } else {
    v = root[k * 32 + o];
    col = 544 + o;
  }
  BtG[(size_t)col * 32 + k] = (half_t)v;
}

// ---------------- S1: per-bucket histogram of src ----------------
__global__ __launch_bounds__(256) void hist_kernel(
    const int* __restrict__ ei, int* __restrict__ hist, int E, int shift) {
  __shared__ int lh[NBUCKET];
  if (threadIdx.x < NBUCKET) lh[threadIdx.x] = 0;
  __syncthreads();
  int e = blockIdx.x * 256 + threadIdx.x;
  if (e < E) atomicAdd(&lh[ei[e] >> shift], 1);
  __syncthreads();
  if (threadIdx.x < NBUCKET && lh[threadIdx.x] > 0)
    atomicAdd(&hist[threadIdx.x], lh[threadIdx.x]);
}

// ---------------- S2: exclusive scan -> cursor ----------------
__global__ __launch_bounds__(256) void scan_kernel(
    const int* __restrict__ hist, int* __restrict__ cursor) {
  if (threadIdx.x == 0) {
    int acc = 0;
    for (int i = 0; i < NBUCKET; ++i) {
      cursor[i] = acc;
      acc += hist[i];
    }
  }
}

// ---------------- S3: ranked scatter -> perm (bucket-ordered edge ids) ----------------
__global__ __launch_bounds__(256) void scatter_kernel(
    const int* __restrict__ ei, int* __restrict__ cursor,
    int* __restrict__ perm, int E, int shift) {
  __shared__ int lh[NBUCKET];
  __shared__ int lbase[NBUCKET];
  if (threadIdx.x < NBUCKET) lh[threadIdx.x] = 0;
  __syncthreads();
  int e = blockIdx.x * 256 + threadIdx.x;
  int bkt = 0, rank = 0;
  if (e < E) {
    bkt = ei[e] >> shift;
    rank = atomicAdd(&lh[bkt], 1);
  }
  __syncthreads();
  if (threadIdx.x < NBUCKET && lh[threadIdx.x] > 0)
    lbase[threadIdx.x] = atomicAdd(&cursor[threadIdx.x], lh[threadIdx.x]);
  __syncthreads();
  if (e < E) perm[lbase[bkt] + rank] = e;
}

// ---------------- K0: MFMA GEMM: [N x 32] @ [32 x 576] ----------------
__global__ __launch_bounds__(256) void gemm_y_mfma_kernel(
    const float* __restrict__ x, const half_t* __restrict__ BtG,
    const float* __restrict__ bias, half_t* __restrict__ Y,
    float* __restrict__ out, int N) {
  __shared__ char BtL[BCOLS * BSTRIDE_B];

  int tid = threadIdx.x;
  for (int t = tid; t < BCOLS * 4; t += 256) {
    int col = t >> 2, part = t & 3;
    *(float4*)(BtL + col * BSTRIDE_B + part * 16) =
        *(const float4*)((const char*)BtG + col * 64 + part * 16);
  }
  __syncthreads();

  int wv = tid >> 6, lane = tid & 63;
  int lr = lane & 15, kg = lane >> 4;
  int n0 = blockIdx.x * 64 + wv * 16;
  int row = n0 + lr;

  f16x8 a;
  if (row < N) {
    float4 u0 = *(const float4*)(x + (size_t)row * 32 + kg * 8);
    float4 u1 = *(const float4*)(x + (size_t)row * 32 + kg * 8 + 4);
    a[0] = (half_t)u0.x; a[1] = (half_t)u0.y; a[2] = (half_t)u0.z; a[3] = (half_t)u0.w;
    a[4] = (half_t)u1.x; a[5] = (half_t)u1.y; a[6] = (half_t)u1.z; a[7] = (half_t)u1.w;
  } else {
    a = (f16x8)(half_t)0.f;
  }

  for (int ct = 0; ct < 36; ++ct) {
    int col = ct * 16 + lr;
    f16x8 bf = *(const f16x8*)(BtL + col * BSTRIDE_B + kg * 16);
    f32x4 c = {0.f, 0.f, 0.f, 0.f};
    c = __builtin_amdgcn_mfma_f32_16x16x32_f16(a, bf, c, 0, 0, 0);
    if (col < 544) {
#pragma unroll
      for (int j = 0; j < 4; ++j) {
        int n = n0 + kg * 4 + j;
        if (n < N) Y[(size_t)n * 544 + col] = (half_t)c[j];
      }
    } else {
      int o = col - 544;
      float bv = bias[o];
#pragma unroll
      for (int j = 0; j < 4; ++j) {
        int n = n0 + kg * 4 + j;
        if (n < N) out[(size_t)n * OUT_F + o] = c[j] + bv;
      }
    }
  }
}

// ---------------- K2: edge kernel over bucket-sorted perm, XCD-chunk swizzle ----------------
__global__ __launch_bounds__(256) void edge_light_kernel(
    const half_t* __restrict__ Y, const float* __restrict__ ef,
    const int* __restrict__ ei, const int* __restrict__ perm,
    float* __restrict__ agg, int E) {
  // bijective XCD chunk swizzle (m204): consecutive sorted positions -> same XCD
  int nwg = gridDim.x;
  int xcd = blockIdx.x & 7, off = blockIdx.x >> 3;
  int q = nwg >> 3, r = nwg & 7;
  int bid = (xcd < r) ? xcd * (q + 1) + off : r * (q + 1) + (xcd - r) * q + off;

  __shared__ float efl[32][17];
  __shared__ float msg[32][33];
  __shared__ int dstl[32];

  int e0 = bid * 32;
  int t = threadIdx.x;
  int el = t >> 3, oq = t & 7;
  int e = e0 + el;
  bool ev = (e < E);
  int pe = ev ? perm[e] : 0;
  int s = ev ? ei[pe] : 0;

  // issue all 17 gather loads up front
  const half_t* yrow = Y + (size_t)s * 544 + oq * 4;
  h4 yv[17];
#pragma unroll
  for (int f = 0; f < 17; ++f) yv[f] = *(const h4*)(yrow + f * 32);
  __builtin_amdgcn_sched_barrier(0);

  if (t < 128) {
    int ep = e0 + (t >> 2);
    int qq = t & 3;
    float4 v = make_float4(0.f, 0.f, 0.f, 0.f);
    if (ep < E) v = *(const float4*)(ef + (size_t)perm[ep] * EDGE_F + qq * 4);
    efl[t >> 2][qq * 4 + 0] = v.x; efl[t >> 2][qq * 4 + 1] = v.y;
    efl[t >> 2][qq * 4 + 2] = v.z; efl[t >> 2][qq * 4 + 3] = v.w;
  }
  if (t < 32) {
    int ep = e0 + t;
    dstl[t] = (ep < E) ? ei[E + perm[ep]] : -1;
  }
  __syncthreads();

  float acc[4];
#pragma unroll
  for (int j = 0; j < 4; ++j) acc[j] = (float)yv[16][j];
#pragma unroll
  for (int f = 0; f < EDGE_F; ++f) {
    float m = efl[el][f];
#pragma unroll
    for (int j = 0; j < 4; ++j) acc[j] = fmaf(m, (float)yv[f][j], acc[j]);
  }
#pragma unroll
  for (int j = 0; j < 4; ++j) msg[el][oq * 4 + j] = acc[j];
  __syncthreads();

  int d = dstl[el];
  if (d >= 0) {
    float* dp = agg + (size_t)d * OUT_F;
#pragma unroll
    for (int j = 0; j < 4; ++j)
      atomicAdd(dp + j * 8 + oq, msg[el][j * 8 + oq]);
  }
}

// ---------------- Fallback path (small ws) ----------------
__global__ __launch_bounds__(256) void node_root_kernel(
    const float* __restrict__ x, const float* __restrict__ root,
    const float* __restrict__ bias, float* __restrict__ agg, int N) {
  __shared__ float rl[IN_F * OUT_F];
  __shared__ float bl[OUT_F];
  for (int t = threadIdx.x; t < IN_F * OUT_F; t += blockDim.x) rl[t] = root[t];
  if (threadIdx.x < OUT_F) bl[threadIdx.x] = bias[threadIdx.x];
  __syncthreads();
  int n = blockIdx.x * blockDim.x + threadIdx.x;
  bool valid = (n < N);
  int nu = valid ? n : 0;
  float xr[IN_F];
  const float4* xp = (const float4*)(x + (size_t)nu * IN_F);
#pragma unroll
  for (int q = 0; q < IN_F / 4; ++q) {
    float4 v = xp[q];
    xr[q * 4 + 0] = v.x; xr[q * 4 + 1] = v.y; xr[q * 4 + 2] = v.z; xr[q * 4 + 3] = v.w;
  }
  float acc[OUT_F];
#pragma unroll
  for (int o = 0; o < OUT_F; ++o) acc[o] = bl[o];
#pragma unroll
  for (int i = 0; i < IN_F; ++i) {
    float xi = xr[i];
#pragma unroll
    for (int o = 0; o < OUT_F; ++o) acc[o] = fmaf(xi, rl[i * OUT_F + o], acc[o]);
  }
  if (valid) {
    float4* op = (float4*)(agg + (size_t)n * OUT_F);
#pragma unroll
    for (int q = 0; q < OUT_F / 4; ++q)
      op[q] = make_float4(acc[q * 4 + 0], acc[q * 4 + 1], acc[q * 4 + 2], acc[q * 4 + 3]);
  }
}

__global__ __launch_bounds__(256) void edge_kernel(
    const float* __restrict__ x, const float* __restrict__ ef,
    const float* __restrict__ W, const float* __restrict__ b,
    const int* __restrict__ ei, float* __restrict__ agg, int E) {
  __shared__ float Wl[EDGE_F * IN_F * OUT_F];
  int e = blockIdx.x * blockDim.x + threadIdx.x;
  bool valid = (e < E);
  int eu = valid ? e : 0;
  int s = ei[eu];
  int d = ei[E + eu];
  float efr[EDGE_F];
  {
    const float4* ep = (const float4*)(ef + (size_t)eu * EDGE_F);
#pragma unroll
    for (int q = 0; q < EDGE_F / 4; ++q) {
      float4 v = ep[q];
      efr[q * 4 + 0] = v.x; efr[q * 4 + 1] = v.y;
      efr[q * 4 + 2] = v.z; efr[q * 4 + 3] = v.w;
    }
  }
  const float* xrow = x + (size_t)s * IN_F;
  float acc[OUT_F];
#pragma unroll
  for (int o = 0; o < OUT_F; ++o) acc[o] = 0.f;
  for (int t = threadIdx.x; t < IN_F * OUT_F; t += 256) Wl[t] = b[t];
  __syncthreads();
  for (int i = 0; i < IN_F; ++i) {
    float xi = xrow[i];
    const float* br = &Wl[i * OUT_F];
#pragma unroll
    for (int o = 0; o < OUT_F; ++o) acc[o] = fmaf(xi, br[o], acc[o]);
  }
  __syncthreads();
  for (int t = threadIdx.x; t < EDGE_F * IN_F * OUT_F / 4; t += 256)
    ((float4*)Wl)[t] = ((const float4*)W)[t];
  __syncthreads();
  for (int i = 0; i < IN_F; ++i) {
    float xi = xrow[i];
#pragma unroll
    for (int f = 0; f < EDGE_F; ++f) {
      float m = efr[f] * xi;
      const float* wr = &Wl[(f * IN_F + i) * OUT_F];
#pragma unroll
      for (int o = 0; o < OUT_F; ++o) acc[o] = fmaf(m, wr[o], acc[o]);
    }
  }
  if (valid) {
    float* dp = agg + (size_t)d * OUT_F;
#pragma unroll
    for (int o = 0; o < OUT_F; ++o) atomicAdd(dp + o, acc[o]);
  }
}

// ---------------- K3: BN stats ----------------
__global__ __launch_bounds__(256) void bn_stats_kernel(
    const float* __restrict__ h, float* __restrict__ stats, int total) {
  int t = blockIdx.x * blockDim.x + threadIdx.x;
  int stride = gridDim.x * blockDim.x;
  float s = 0.f, s2 = 0.f;
  for (int idx = t; idx < total; idx += stride) {
    float v = h[idx];
    s += v;
    s2 = fmaf(v, v, s2);
  }
  __shared__ float ls[256], ls2[256];
  ls[threadIdx.x] = s;
  ls2[threadIdx.x] = s2;
  __syncthreads();
  if (threadIdx.x < 32) {
    float a = ls[threadIdx.x], a2 = ls2[threadIdx.x];
    for (int j = 32 + threadIdx.x; j < 256; j += 32) { a += ls[j]; a2 += ls2[j]; }
    atomicAdd(&stats[threadIdx.x], a);
    atomicAdd(&stats[32 + threadIdx.x], a2);
  }
}

// ---------------- K4: normalize + affine + LeakyReLU ----------------
__global__ __launch_bounds__(256) void bn_apply_kernel(
    float* __restrict__ h, const float* __restrict__ stats,
    const float* __restrict__ gamma, const float* __restrict__ beta,
    int total, float invN) {
  int t = blockIdx.x * blockDim.x + threadIdx.x;
  int i4 = t * 4;
  if (i4 >= total) return;
  float4 v = *(const float4*)(h + i4);
  float r[4] = {v.x, v.y, v.z, v.w};
  int o0 = i4 & 31;
#pragma unroll
  for (int j = 0; j < 4; ++j) {
    int o = o0 + j;
    float m = stats[o] * invN;
    float var = fmaf(-m, m, stats[32 + o] * invN);
    float sc = rsqrtf(var + BN_EPS) * gamma[o];
    float val = (r[j] - m) * sc + beta[o];
    r[j] = val >= 0.f ? val : SLOPE * val;
  }
  *(float4*)(h + i4) = make_float4(r[0], r[1], r[2], r[3]);
}

extern "C" void kernel_launch(void* const* d_in, const int* in_sizes, int n_in,
                              void* d_out, int out_size, void* d_ws, size_t ws_size,
                              hipStream_t stream) {
  const float* x     = (const float*)d_in[0];
  const float* ef    = (const float*)d_in[1];
  const float* W     = (const float*)d_in[2];
  const float* b     = (const float*)d_in[3];
  const float* root  = (const float*)d_in[4];
  const float* bias  = (const float*)d_in[5];
  const float* gamma = (const float*)d_in[6];
  const float* beta  = (const float*)d_in[7];
  const int*   ei    = (const int*)d_in[8];

  int N = in_sizes[0] / IN_F;
  int E = in_sizes[1] / EDGE_F;
  int total = N * OUT_F;

  float* out = (float*)d_out;
  char* wsb = (char*)d_ws;
  float*  stats  = (float*)wsb;                        // 64 f
  half_t* BtG    = (half_t*)(wsb + 1024);              // 36864 B
  int*    hist   = (int*)(wsb + 1024 + 36864);         // 128 i
  int*    cursor = (int*)(wsb + 1024 + 36864 + 512);   // 128 i
  int*    perm   = (int*)(wsb + 1024 + 36864 + 1024);  // E ints
  size_t yoff = 1024 + 36864 + 1024 + (((size_t)E * 4 + 1023) & ~(size_t)1023);
  half_t* Y = (half_t*)(wsb + yoff);

  // bucket shift: (N-1)>>shift must be < NBUCKET
  int shift = 10;
  while (((N - 1) >> shift) >= NBUCKET) ++shift;

  size_t need = yoff + (size_t)N * 544 * sizeof(half_t);

  if (ws_size >= need) {
    prep_bt_kernel<<<(BCOLS * 32 + 255) / 256, 256, 0, stream>>>(W, b, root, BtG, stats, hist);
    hist_kernel<<<(E + 255) / 256, 256, 0, stream>>>(ei, hist, E, shift);
    scan_kernel<<<1, 256, 0, stream>>>(hist, cursor);
    scatter_kernel<<<(E + 255) / 256, 256, 0, stream>>>(ei, cursor, perm, E, shift);
    gemm_y_mfma_kernel<<<(N + 63) / 64, 256, 0, stream>>>(x, BtG, bias, Y, out, N);
    edge_light_kernel<<<(E + 31) / 32, 256, 0, stream>>>(Y, ef, ei, perm, out, E);
  } else {
    hipMemsetAsync(stats, 0, 64 * sizeof(float), stream);
    node_root_kernel<<<(N + 255) / 256, 256, 0, stream>>>(x, root, bias, out, N);
    edge_kernel<<<(E + 255) / 256, 256, 0, stream>>>(x, ef, W, b, ei, out, E);
  }
  bn_stats_kernel<<<1024, 256, 0, stream>>>(out, stats, total);
  bn_apply_kernel<<<(total / 4 + 255) / 256, 256, 0, stream>>>(out, stats, gamma, beta, total, 1.0f / (float)N);
}

// Round 8
// 238.904 us; speedup vs baseline: 1.0139x; 1.0139x over previous
//
#include <hip/hip_runtime.h>

#define IN_F 32
#define OUT_F 32
#define EDGE_F 16
#define BN_EPS 1e-5f
#define SLOPE 0.01f
#define NBUCKET 128

typedef _Float16 half_t;
typedef __attribute__((ext_vector_type(4))) _Float16 h4;
typedef __attribute__((ext_vector_type(8))) _Float16 f16x8;
typedef __attribute__((ext_vector_type(4))) float f32x4;

#define BCOLS 576
#define BSTRIDE_B 80

// ---------------- P0: build Bt[col][k] fp16; block 0 zeroes stats+hist ----------------
__global__ __launch_bounds__(256) void prep_bt_kernel(
    const float* __restrict__ W, const float* __restrict__ b,
    const float* __restrict__ root, half_t* __restrict__ BtG,
    float* __restrict__ stats, int* __restrict__ hist) {
  if (blockIdx.x == 0) {
    if (threadIdx.x < 64) stats[threadIdx.x] = 0.f;
    else if (threadIdx.x < 64 + NBUCKET) hist[threadIdx.x - 64] = 0;
  }
  int idx = blockIdx.x * 256 + threadIdx.x;
  if (idx >= BCOLS * 32) return;
  int o = idx & 31;
  int k = (idx >> 5) & 31;
  int fp = idx >> 10;
  float v;
  int col;
  if (fp < 16) {
    v = W[(size_t)fp * 1024 + k * 32 + o];
    col = fp * 32 + o;
  } else if (fp == 16) {
    v = b[k * 32 + o];
    col = 512 + o;
  } else {
    v = root[k * 32 + o];
    col = 544 + o;
  }
  BtG[(size_t)col * 32 + k] = (half_t)v;
}

// ---------------- S1: per-bucket histogram of src ----------------
__global__ __launch_bounds__(256) void hist_kernel(
    const int* __restrict__ ei, int* __restrict__ hist, int E, int shift) {
  __shared__ int lh[NBUCKET];
  if (threadIdx.x < NBUCKET) lh[threadIdx.x] = 0;
  __syncthreads();
  int e = blockIdx.x * 256 + threadIdx.x;
  if (e < E) atomicAdd(&lh[ei[e] >> shift], 1);
  __syncthreads();
  if (threadIdx.x < NBUCKET && lh[threadIdx.x] > 0)
    atomicAdd(&hist[threadIdx.x], lh[threadIdx.x]);
}

// ---------------- S2: exclusive scan (parallel, 128 wide) ----------------
__global__ __launch_bounds__(NBUCKET) void scan_kernel(
    const int* __restrict__ hist, int* __restrict__ cursor) {
  __shared__ int tmp[NBUCKET];
  int t = threadIdx.x;
  tmp[t] = hist[t];
  __syncthreads();
  int acc = 0;
  for (int i = 0; i < t; ++i) acc += tmp[i];  // LDS, ~127 adds worst lane: trivial
  cursor[t] = acc;
}

// ---------------- S3: ranked scatter -> perm ----------------
__global__ __launch_bounds__(256) void scatter_kernel(
    const int* __restrict__ ei, int* __restrict__ cursor,
    int* __restrict__ perm, int E, int shift) {
  __shared__ int lh[NBUCKET];
  __shared__ int lbase[NBUCKET];
  if (threadIdx.x < NBUCKET) lh[threadIdx.x] = 0;
  __syncthreads();
  int e = blockIdx.x * 256 + threadIdx.x;
  int bkt = 0, rank = 0;
  if (e < E) {
    bkt = ei[e] >> shift;
    rank = atomicAdd(&lh[bkt], 1);
  }
  __syncthreads();
  if (threadIdx.x < NBUCKET && lh[threadIdx.x] > 0)
    lbase[threadIdx.x] = atomicAdd(&cursor[threadIdx.x], lh[threadIdx.x]);
  __syncthreads();
  if (e < E) perm[lbase[bkt] + rank] = e;
}

// ---------------- K0: MFMA GEMM [N x 32] @ [32 x 576], LDS-bounced vector stores ----------------
__global__ __launch_bounds__(256) void gemm_y_mfma_kernel(
    const float* __restrict__ x, const half_t* __restrict__ BtG,
    const float* __restrict__ bias, half_t* __restrict__ Y,
    float* __restrict__ out, int N) {
  __shared__ char BtL[BCOLS * BSTRIDE_B];     // 46080 B
  __shared__ float tile[4][16][18];           // per-wave bounce, 2-way max conflict

  int tid = threadIdx.x;
  for (int t = tid; t < BCOLS * 4; t += 256) {
    int col = t >> 2, part = t & 3;
    *(float4*)(BtL + col * BSTRIDE_B + part * 16) =
        *(const float4*)((const char*)BtG + col * 64 + part * 16);
  }
  __syncthreads();

  int wv = tid >> 6, lane = tid & 63;
  int lr = lane & 15, kg = lane >> 4;
  int n0 = blockIdx.x * 64 + wv * 16;
  int row = n0 + lr;

  f16x8 a;
  if (row < N) {
    float4 u0 = *(const float4*)(x + (size_t)row * 32 + kg * 8);
    float4 u1 = *(const float4*)(x + (size_t)row * 32 + kg * 8 + 4);
    a[0] = (half_t)u0.x; a[1] = (half_t)u0.y; a[2] = (half_t)u0.z; a[3] = (half_t)u0.w;
    a[4] = (half_t)u1.x; a[5] = (half_t)u1.y; a[6] = (half_t)u1.z; a[7] = (half_t)u1.w;
  } else {
    a = (f16x8)(half_t)0.f;
  }

  int rr = lane & 15, qq = lane >> 4;  // read-phase role: row rr, col-quad qq
  int nst = n0 + rr;

  for (int ct = 0; ct < 36; ++ct) {
    int col = ct * 16 + lr;
    f16x8 bf = *(const f16x8*)(BtL + col * BSTRIDE_B + kg * 16);
    f32x4 c = {0.f, 0.f, 0.f, 0.f};
    c = __builtin_amdgcn_mfma_f32_16x16x32_f16(a, bf, c, 0, 0, 0);
    // bounce through wave-local LDS: tile[r][lc]
#pragma unroll
    for (int j = 0; j < 4; ++j) tile[wv][kg * 4 + j][lr] = c[j];
    __builtin_amdgcn_wave_barrier();  // wave-synchronous; no block barrier needed
    if (nst < N) {
      float v0 = tile[wv][rr][qq * 4 + 0];
      float v1 = tile[wv][rr][qq * 4 + 1];
      float v2 = tile[wv][rr][qq * 4 + 2];
      float v3 = tile[wv][rr][qq * 4 + 3];
      if (ct < 34) {
        h4 hv;
        hv[0] = (half_t)v0; hv[1] = (half_t)v1; hv[2] = (half_t)v2; hv[3] = (half_t)v3;
        *(h4*)(Y + (size_t)nst * 544 + ct * 16 + qq * 4) = hv;
      } else {
        int o = (ct - 34) * 16 + qq * 4;
        float4 bv = *(const float4*)(bias + o);
        *(float4*)(out + (size_t)nst * OUT_F + o) =
            make_float4(v0 + bv.x, v1 + bv.y, v2 + bv.z, v3 + bv.w);
      }
    }
    __builtin_amdgcn_wave_barrier();
  }
}

// ---------------- K2: edge kernel — asm load cluster, bucket-sorted, sector atomics ----------------
__global__ __launch_bounds__(256) void edge_light_kernel(
    const half_t* __restrict__ Y, const float* __restrict__ ef,
    const int* __restrict__ ei, const int* __restrict__ perm,
    float* __restrict__ agg, int E) {
  // bijective XCD chunk swizzle: consecutive sorted positions -> same XCD
  int nwg = gridDim.x;
  int xcd = blockIdx.x & 7, off = blockIdx.x >> 3;
  int q = nwg >> 3, r = nwg & 7;
  int bid = (xcd < r) ? xcd * (q + 1) + off : r * (q + 1) + (xcd - r) * q + off;

  __shared__ float efl[32][17];
  __shared__ float msg[32][33];
  __shared__ int dstl[32];

  int e0 = bid * 32;
  int t = threadIdx.x;
  int el = t >> 3, oq = t & 7;
  int e = e0 + el;
  bool ev = (e < E);
  int pe = ev ? perm[e] : 0;
  int s = ev ? ei[pe] : 0;

  // 17 gather loads forced in-flight via inline asm (compiler cannot serialize)
  const half_t* yrow = Y + (size_t)s * 544 + oq * 4;
  h4 yv[17];
#pragma unroll
  for (int f = 0; f < 17; ++f) {
    asm volatile("global_load_dwordx2 %0, %1, off offset:%2"
                 : "=v"(yv[f])
                 : "v"(yrow), "i"(f * 64));
  }

  // overlap: stage ef + dst while gathers are in flight
  if (t < 128) {
    int ep = e0 + (t >> 2);
    int qq = t & 3;
    float4 v = make_float4(0.f, 0.f, 0.f, 0.f);
    if (ep < E) v = *(const float4*)(ef + (size_t)perm[ep] * EDGE_F + qq * 4);
    efl[t >> 2][qq * 4 + 0] = v.x; efl[t >> 2][qq * 4 + 1] = v.y;
    efl[t >> 2][qq * 4 + 2] = v.z; efl[t >> 2][qq * 4 + 3] = v.w;
  }
  if (t < 32) {
    int ep = e0 + t;
    dstl[t] = (ep < E) ? ei[E + perm[ep]] : -1;
  }
  __syncthreads();

  asm volatile("s_waitcnt vmcnt(0)" ::: "memory");
  __builtin_amdgcn_sched_barrier(0);

  float acc[4];
#pragma unroll
  for (int j = 0; j < 4; ++j) acc[j] = (float)yv[16][j];
#pragma unroll
  for (int f = 0; f < EDGE_F; ++f) {
    float m = efl[el][f];
#pragma unroll
    for (int j = 0; j < 4; ++j) acc[j] = fmaf(m, (float)yv[f][j], acc[j]);
  }
#pragma unroll
  for (int j = 0; j < 4; ++j) msg[el][oq * 4 + j] = acc[j];
  __syncthreads();

  int d = dstl[el];
  if (d >= 0) {
    float* dp = agg + (size_t)d * OUT_F;
#pragma unroll
    for (int j = 0; j < 4; ++j)
      atomicAdd(dp + j * 8 + oq, msg[el][j * 8 + oq]);
  }
}

// ---------------- Fallback path (small ws) ----------------
__global__ __launch_bounds__(256) void node_root_kernel(
    const float* __restrict__ x, const float* __restrict__ root,
    const float* __restrict__ bias, float* __restrict__ agg, int N) {
  __shared__ float rl[IN_F * OUT_F];
  __shared__ float bl[OUT_F];
  for (int t = threadIdx.x; t < IN_F * OUT_F; t += blockDim.x) rl[t] = root[t];
  if (threadIdx.x < OUT_F) bl[threadIdx.x] = bias[threadIdx.x];
  __syncthreads();
  int n = blockIdx.x * blockDim.x + threadIdx.x;
  bool valid = (n < N);
  int nu = valid ? n : 0;
  float xr[IN_F];
  const float4* xp = (const float4*)(x + (size_t)nu * IN_F);
#pragma unroll
  for (int q = 0; q < IN_F / 4; ++q) {
    float4 v = xp[q];
    xr[q * 4 + 0] = v.x; xr[q * 4 + 1] = v.y; xr[q * 4 + 2] = v.z; xr[q * 4 + 3] = v.w;
  }
  float acc[OUT_F];
#pragma unroll
  for (int o = 0; o < OUT_F; ++o) acc[o] = bl[o];
#pragma unroll
  for (int i = 0; i < IN_F; ++i) {
    float xi = xr[i];
#pragma unroll
    for (int o = 0; o < OUT_F; ++o) acc[o] = fmaf(xi, rl[i * OUT_F + o], acc[o]);
  }
  if (valid) {
    float4* op = (float4*)(agg + (size_t)n * OUT_F);
#pragma unroll
    for (int q = 0; q < OUT_F / 4; ++q)
      op[q] = make_float4(acc[q * 4 + 0], acc[q * 4 + 1], acc[q * 4 + 2], acc[q * 4 + 3]);
  }
}

__global__ __launch_bounds__(256) void edge_kernel(
    const float* __restrict__ x, const float* __restrict__ ef,
    const float* __restrict__ W, const float* __restrict__ b,
    const int* __restrict__ ei, float* __restrict__ agg, int E) {
  __shared__ float Wl[EDGE_F * IN_F * OUT_F];
  int e = blockIdx.x * blockDim.x + threadIdx.x;
  bool valid = (e < E);
  int eu = valid ? e : 0;
  int s = ei[eu];
  int d = ei[E + eu];
  float efr[EDGE_F];
  {
    const float4* ep = (const float4*)(ef + (size_t)eu * EDGE_F);
#pragma unroll
    for (int q = 0; q < EDGE_F / 4; ++q) {
      float4 v = ep[q];
      efr[q * 4 + 0] = v.x; efr[q * 4 + 1] = v.y;
      efr[q * 4 + 2] = v.z; efr[q * 4 + 3] = v.w;
    }
  }
  const float* xrow = x + (size_t)s * IN_F;
  float acc[OUT_F];
#pragma unroll
  for (int o = 0; o < OUT_F; ++o) acc[o] = 0.f;
  for (int t = threadIdx.x; t < IN_F * OUT_F; t += 256) Wl[t] = b[t];
  __syncthreads();
  for (int i = 0; i < IN_F; ++i) {
    float xi = xrow[i];
    const float* br = &Wl[i * OUT_F];
#pragma unroll
    for (int o = 0; o < OUT_F; ++o) acc[o] = fmaf(xi, br[o], acc[o]);
  }
  __syncthreads();
  for (int t = threadIdx.x; t < EDGE_F * IN_F * OUT_F / 4; t += 256)
    ((float4*)Wl)[t] = ((const float4*)W)[t];
  __syncthreads();
  for (int i = 0; i < IN_F; ++i) {
    float xi = xrow[i];
#pragma unroll
    for (int f = 0; f < EDGE_F; ++f) {
      float m = efr[f] * xi;
      const float* wr = &Wl[(f * IN_F + i) * OUT_F];
#pragma unroll
      for (int o = 0; o < OUT_F; ++o) acc[o] = fmaf(m, wr[o], acc[o]);
    }
  }
  if (valid) {
    float* dp = agg + (size_t)d * OUT_F;
#pragma unroll
    for (int o = 0; o < OUT_F; ++o) atomicAdd(dp + o, acc[o]);
  }
}

// ---------------- K3: BN stats ----------------
__global__ __launch_bounds__(256) void bn_stats_kernel(
    const float* __restrict__ h, float* __restrict__ stats, int total) {
  int t = blockIdx.x * blockDim.x + threadIdx.x;
  int stride = gridDim.x * blockDim.x;
  float s = 0.f, s2 = 0.f;
  for (int idx = t; idx < total; idx += stride) {
    float v = h[idx];
    s += v;
    s2 = fmaf(v, v, s2);
  }
  __shared__ float ls[256], ls2[256];
  ls[threadIdx.x] = s;
  ls2[threadIdx.x] = s2;
  __syncthreads();
  if (threadIdx.x < 32) {
    float a = ls[threadIdx.x], a2 = ls2[threadIdx.x];
    for (int j = 32 + threadIdx.x; j < 256; j += 32) { a += ls[j]; a2 += ls2[j]; }
    atomicAdd(&stats[threadIdx.x], a);
    atomicAdd(&stats[32 + threadIdx.x], a2);
  }
}

// ---------------- K4: normalize + affine + LeakyReLU ----------------
__global__ __launch_bounds__(256) void bn_apply_kernel(
    float* __restrict__ h, const float* __restrict__ stats,
    const float* __restrict__ gamma, const float* __restrict__ beta,
    int total, float invN) {
  int t = blockIdx.x * blockDim.x + threadIdx.x;
  int i4 = t * 4;
  if (i4 >= total) return;
  float4 v = *(const float4*)(h + i4);
  float r[4] = {v.x, v.y, v.z, v.w};
  int o0 = i4 & 31;
#pragma unroll
  for (int j = 0; j < 4; ++j) {
    int o = o0 + j;
    float m = stats[o] * invN;
    float var = fmaf(-m, m, stats[32 + o] * invN);
    float sc = rsqrtf(var + BN_EPS) * gamma[o];
    float val = (r[j] - m) * sc + beta[o];
    r[j] = val >= 0.f ? val : SLOPE * val;
  }
  *(float4*)(h + i4) = make_float4(r[0], r[1], r[2], r[3]);
}

extern "C" void kernel_launch(void* const* d_in, const int* in_sizes, int n_in,
                              void* d_out, int out_size, void* d_ws, size_t ws_size,
                              hipStream_t stream) {
  const float* x     = (const float*)d_in[0];
  const float* ef    = (const float*)d_in[1];
  const float* W     = (const float*)d_in[2];
  const float* b     = (const float*)d_in[3];
  const float* root  = (const float*)d_in[4];
  const float* bias  = (const float*)d_in[5];
  const float* gamma = (const float*)d_in[6];
  const float* beta  = (const float*)d_in[7];
  const int*   ei    = (const int*)d_in[8];

  int N = in_sizes[0] / IN_F;
  int E = in_sizes[1] / EDGE_F;
  int total = N * OUT_F;

  float* out = (float*)d_out;
  char* wsb = (char*)d_ws;
  float*  stats  = (float*)wsb;                        // 64 f
  half_t* BtG    = (half_t*)(wsb + 1024);              // 36864 B
  int*    hist   = (int*)(wsb + 1024 + 36864);         // 128 i
  int*    cursor = (int*)(wsb + 1024 + 36864 + 512);   // 128 i
  int*    perm   = (int*)(wsb + 1024 + 36864 + 1024);  // E ints
  size_t yoff = 1024 + 36864 + 1024 + (((size_t)E * 4 + 1023) & ~(size_t)1023);
  half_t* Y = (half_t*)(wsb + yoff);

  int shift = 10;
  while (((N - 1) >> shift) >= NBUCKET) ++shift;

  size_t need = yoff + (size_t)N * 544 * sizeof(half_t);

  if (ws_size >= need) {
    prep_bt_kernel<<<(BCOLS * 32 + 255) / 256, 256, 0, stream>>>(W, b, root, BtG, stats, hist);
    hist_kernel<<<(E + 255) / 256, 256, 0, stream>>>(ei, hist, E, shift);
    scan_kernel<<<1, NBUCKET, 0, stream>>>(hist, cursor);
    scatter_kernel<<<(E + 255) / 256, 256, 0, stream>>>(ei, cursor, perm, E, shift);
    gemm_y_mfma_kernel<<<(N + 63) / 64, 256, 0, stream>>>(x, BtG, bias, Y, out, N);
    edge_light_kernel<<<(E + 31) / 32, 256, 0, stream>>>(Y, ef, ei, perm, out, E);
  } else {
    hipMemsetAsync(stats, 0, 64 * sizeof(float), stream);
    node_root_kernel<<<(N + 255) / 256, 256, 0, stream>>>(x, root, bias, out, N);
    edge_kernel<<<(E + 255) / 256, 256, 0, stream>>>(x, ef, W, b, ei, out, E);
  }
  bn_stats_kernel<<<1024, 256, 0, stream>>>(out, stats, total);
  bn_apply_kernel<<<(total / 4 + 255) / 256, 256, 0, stream>>>(out, stats, gamma, beta, total, 1.0f / (float)N);
}

// Round 9
// 222.321 us; speedup vs baseline: 1.0896x; 1.0746x over previous
//
#include <hip/hip_runtime.h>

#define IN_F 32
#define OUT_F 32
#define EDGE_F 16
#define BN_EPS 1e-5f
#define SLOPE 0.01f

typedef _Float16 half_t;
typedef __attribute__((ext_vector_type(4))) _Float16 h4;
typedef __attribute__((ext_vector_type(8))) _Float16 f16x8;
typedef __attribute__((ext_vector_type(4))) float f32x4;

#define BCOLS 576
#define BSTRIDE_B 80

// ---------------- P0: build Bt[col][k] fp16 ----------------
__global__ __launch_bounds__(256) void prep_bt_kernel(
    const float* __restrict__ W, const float* __restrict__ b,
    const float* __restrict__ root, half_t* __restrict__ BtG) {
  int idx = blockIdx.x * 256 + threadIdx.x;
  if (idx >= BCOLS * 32) return;
  int o = idx & 31;
  int k = (idx >> 5) & 31;
  int fp = idx >> 10;
  float v;
  int col;
  if (fp < 16) {
    v = W[(size_t)fp * 1024 + k * 32 + o];
    col = fp * 32 + o;
  } else if (fp == 16) {
    v = b[k * 32 + o];
    col = 512 + o;
  } else {
    v = root[k * 32 + o];
    col = 544 + o;
  }
  BtG[(size_t)col * 32 + k] = (half_t)v;
}

// ---------------- dst-CSR sort ----------------
__global__ __launch_bounds__(256) void histd_kernel(
    const int* __restrict__ ei, int* __restrict__ cnt, int E) {
  int e = blockIdx.x * 256 + threadIdx.x;
  if (e < E) atomicAdd(&cnt[ei[E + e]], 1);
}

__global__ __launch_bounds__(256) void scan_a_kernel(
    const int* __restrict__ cnt, int* __restrict__ rp, int* __restrict__ bsum, int N) {
  __shared__ int lds[256];
  int i = blockIdx.x * 256 + threadIdx.x;
  int v = (i < N) ? cnt[i] : 0;
  lds[threadIdx.x] = v;
  __syncthreads();
  int ex = 0;
  for (int j = 0; j < threadIdx.x; ++j) ex += lds[j];
  if (i < N) rp[i] = ex;
  if (threadIdx.x == 255) bsum[blockIdx.x] = ex + v;
}

__global__ __launch_bounds__(512) void scan_b_kernel(
    const int* __restrict__ bsum, int* __restrict__ bcur, int nb) {
  __shared__ int lds[512];
  int t = threadIdx.x;
  lds[t] = (t < nb) ? bsum[t] : 0;
  __syncthreads();
  int ex = 0;
  for (int j = 0; j < t; ++j) ex += lds[j];
  if (t < nb) bcur[t] = ex;
}

__global__ __launch_bounds__(256) void scan_c_kernel(
    int* __restrict__ rp, int* __restrict__ cursor,
    const int* __restrict__ bcur, int N, int E) {
  int i = blockIdx.x * 256 + threadIdx.x;
  if (i < N) {
    int v = rp[i] + bcur[i >> 8];
    rp[i] = v;
    cursor[i] = v;
  }
  if (i == 0) rp[N] = E;
}

__global__ __launch_bounds__(256) void scatterd_kernel(
    const int* __restrict__ ei, int* __restrict__ cursor,
    int* __restrict__ permd, int E) {
  int e = blockIdx.x * 256 + threadIdx.x;
  if (e < E) {
    int d = ei[E + e];
    int r = atomicAdd(&cursor[d], 1);
    permd[r] = e;
  }
}

// ---------------- K0: MFMA GEMM [N x 32] @ [32 x 576] ----------------
__global__ __launch_bounds__(256) void gemm_y_mfma_kernel(
    const float* __restrict__ x, const half_t* __restrict__ BtG,
    const float* __restrict__ bias, half_t* __restrict__ Y,
    float* __restrict__ out, int N) {
  __shared__ char BtL[BCOLS * BSTRIDE_B];
  __shared__ float tile[4][16][18];

  int tid = threadIdx.x;
  for (int t = tid; t < BCOLS * 4; t += 256) {
    int col = t >> 2, part = t & 3;
    *(float4*)(BtL + col * BSTRIDE_B + part * 16) =
        *(const float4*)((const char*)BtG + col * 64 + part * 16);
  }
  __syncthreads();

  int wv = tid >> 6, lane = tid & 63;
  int lr = lane & 15, kg = lane >> 4;
  int n0 = blockIdx.x * 64 + wv * 16;
  int row = n0 + lr;

  f16x8 a;
  if (row < N) {
    float4 u0 = *(const float4*)(x + (size_t)row * 32 + kg * 8);
    float4 u1 = *(const float4*)(x + (size_t)row * 32 + kg * 8 + 4);
    a[0] = (half_t)u0.x; a[1] = (half_t)u0.y; a[2] = (half_t)u0.z; a[3] = (half_t)u0.w;
    a[4] = (half_t)u1.x; a[5] = (half_t)u1.y; a[6] = (half_t)u1.z; a[7] = (half_t)u1.w;
  } else {
    a = (f16x8)(half_t)0.f;
  }

  int rr = lane & 15, qq = lane >> 4;
  int nst = n0 + rr;

  for (int ct = 0; ct < 36; ++ct) {
    int col = ct * 16 + lr;
    f16x8 bf = *(const f16x8*)(BtL + col * BSTRIDE_B + kg * 16);
    f32x4 c = {0.f, 0.f, 0.f, 0.f};
    c = __builtin_amdgcn_mfma_f32_16x16x32_f16(a, bf, c, 0, 0, 0);
#pragma unroll
    for (int j = 0; j < 4; ++j) tile[wv][kg * 4 + j][lr] = c[j];
    __builtin_amdgcn_wave_barrier();
    if (nst < N) {
      float v0 = tile[wv][rr][qq * 4 + 0];
      float v1 = tile[wv][rr][qq * 4 + 1];
      float v2 = tile[wv][rr][qq * 4 + 2];
      float v3 = tile[wv][rr][qq * 4 + 3];
      if (ct < 34) {
        h4 hv;
        hv[0] = (half_t)v0; hv[1] = (half_t)v1; hv[2] = (half_t)v2; hv[3] = (half_t)v3;
        *(h4*)(Y + (size_t)nst * 544 + ct * 16 + qq * 4) = hv;
      } else {
        int o = (ct - 34) * 16 + qq * 4;
        float4 bv = *(const float4*)(bias + o);
        *(float4*)(out + (size_t)nst * OUT_F + o) =
            make_float4(v0 + bv.x, v1 + bv.y, v2 + bv.z, v3 + bv.w);
      }
    }
    __builtin_amdgcn_wave_barrier();
  }
}

// ---------------- Pass A: per-edge message, NO atomics, coalesced fp16 store ----------------
__global__ __launch_bounds__(256) void edge_msg_kernel(
    const half_t* __restrict__ Y, const float* __restrict__ ef,
    const int* __restrict__ ei, half_t* __restrict__ msg, int E) {
  __shared__ float efl[32][17];

  int e0 = blockIdx.x * 32;
  int t = threadIdx.x;
  int el = t >> 3, oq = t & 7;
  int e = e0 + el;
  bool ev = (e < E);
  int s = ev ? ei[e] : 0;

  const half_t* yrow = Y + (size_t)s * 544 + oq * 4;
  h4 yv[17];
#pragma unroll
  for (int f = 0; f < 17; ++f) {
    asm volatile("global_load_dwordx2 %0, %1, off offset:%2"
                 : "=v"(yv[f])
                 : "v"(yrow), "i"(f * 64));
  }

  // ef rows e0..e0+31 are contiguous: perfectly coalesced stage
  if (t < 128) {
    int ee = e0 + (t >> 2);
    int qq = t & 3;
    float4 v = make_float4(0.f, 0.f, 0.f, 0.f);
    if (ee < E) v = *(const float4*)(ef + (size_t)ee * EDGE_F + qq * 4);
    efl[t >> 2][qq * 4 + 0] = v.x; efl[t >> 2][qq * 4 + 1] = v.y;
    efl[t >> 2][qq * 4 + 2] = v.z; efl[t >> 2][qq * 4 + 3] = v.w;
  }
  __syncthreads();

  asm volatile("s_waitcnt vmcnt(0)" ::: "memory");
  __builtin_amdgcn_sched_barrier(0);

  float acc[4];
#pragma unroll
  for (int j = 0; j < 4; ++j) acc[j] = (float)yv[16][j];
#pragma unroll
  for (int f = 0; f < EDGE_F; ++f) {
    float m = efl[el][f];
#pragma unroll
    for (int j = 0; j < 4; ++j) acc[j] = fmaf(m, (float)yv[f][j], acc[j]);
  }

  if (ev) {
    h4 hv;
    hv[0] = (half_t)acc[0]; hv[1] = (half_t)acc[1];
    hv[2] = (half_t)acc[2]; hv[3] = (half_t)acc[3];
    *(h4*)(msg + (size_t)e * 32 + oq * 4) = hv;  // 64B/edge, wave writes 512B contiguous
  }
}

// ---------------- Pass B: segment-reduce by dst (no atomics) ----------------
__global__ __launch_bounds__(256) void node_agg_kernel(
    const half_t* __restrict__ msg, const int* __restrict__ rp,
    const int* __restrict__ permd, float* __restrict__ out, int N) {
  int g = threadIdx.x >> 3, oq = threadIdx.x & 7;
  int n = blockIdx.x * 32 + g;
  if (n >= N) return;
  int kb = rp[n], ke = rp[n + 1];
  float4 acc = *(const float4*)(out + (size_t)n * 32 + oq * 4);  // h0 from gemm
  for (int k = kb; k < ke; ++k) {
    int e = permd[k];
    h4 v = *(const h4*)(msg + (size_t)e * 32 + oq * 4);
    acc.x += (float)v[0]; acc.y += (float)v[1];
    acc.z += (float)v[2]; acc.w += (float)v[3];
  }
  *(float4*)(out + (size_t)n * 32 + oq * 4) = acc;
}

// ---------------- Fallback path (small ws) ----------------
__global__ __launch_bounds__(256) void node_root_kernel(
    const float* __restrict__ x, const float* __restrict__ root,
    const float* __restrict__ bias, float* __restrict__ agg, int N) {
  __shared__ float rl[IN_F * OUT_F];
  __shared__ float bl[OUT_F];
  for (int t = threadIdx.x; t < IN_F * OUT_F; t += blockDim.x) rl[t] = root[t];
  if (threadIdx.x < OUT_F) bl[threadIdx.x] = bias[threadIdx.x];
  __syncthreads();
  int n = blockIdx.x * blockDim.x + threadIdx.x;
  bool valid = (n < N);
  int nu = valid ? n : 0;
  float xr[IN_F];
  const float4* xp = (const float4*)(x + (size_t)nu * IN_F);
#pragma unroll
  for (int q = 0; q < IN_F / 4; ++q) {
    float4 v = xp[q];
    xr[q * 4 + 0] = v.x; xr[q * 4 + 1] = v.y; xr[q * 4 + 2] = v.z; xr[q * 4 + 3] = v.w;
  }
  float acc[OUT_F];
#pragma unroll
  for (int o = 0; o < OUT_F; ++o) acc[o] = bl[o];
#pragma unroll
  for (int i = 0; i < IN_F; ++i) {
    float xi = xr[i];
#pragma unroll
    for (int o = 0; o < OUT_F; ++o) acc[o] = fmaf(xi, rl[i * OUT_F + o], acc[o]);
  }
  if (valid) {
    float4* op = (float4*)(agg + (size_t)n * OUT_F);
#pragma unroll
    for (int q = 0; q < OUT_F / 4; ++q)
      op[q] = make_float4(acc[q * 4 + 0], acc[q * 4 + 1], acc[q * 4 + 2], acc[q * 4 + 3]);
  }
}

__global__ __launch_bounds__(256) void edge_kernel(
    const float* __restrict__ x, const float* __restrict__ ef,
    const float* __restrict__ W, const float* __restrict__ b,
    const int* __restrict__ ei, float* __restrict__ agg, int E) {
  __shared__ float Wl[EDGE_F * IN_F * OUT_F];
  int e = blockIdx.x * blockDim.x + threadIdx.x;
  bool valid = (e < E);
  int eu = valid ? e : 0;
  int s = ei[eu];
  int d = ei[E + eu];
  float efr[EDGE_F];
  {
    const float4* ep = (const float4*)(ef + (size_t)eu * EDGE_F);
#pragma unroll
    for (int q = 0; q < EDGE_F / 4; ++q) {
      float4 v = ep[q];
      efr[q * 4 + 0] = v.x; efr[q * 4 + 1] = v.y;
      efr[q * 4 + 2] = v.z; efr[q * 4 + 3] = v.w;
    }
  }
  const float* xrow = x + (size_t)s * IN_F;
  float acc[OUT_F];
#pragma unroll
  for (int o = 0; o < OUT_F; ++o) acc[o] = 0.f;
  for (int t = threadIdx.x; t < IN_F * OUT_F; t += 256) Wl[t] = b[t];
  __syncthreads();
  for (int i = 0; i < IN_F; ++i) {
    float xi = xrow[i];
    const float* br = &Wl[i * OUT_F];
#pragma unroll
    for (int o = 0; o < OUT_F; ++o) acc[o] = fmaf(xi, br[o], acc[o]);
  }
  __syncthreads();
  for (int t = threadIdx.x; t < EDGE_F * IN_F * OUT_F / 4; t += 256)
    ((float4*)Wl)[t] = ((const float4*)W)[t];
  __syncthreads();
  for (int i = 0; i < IN_F; ++i) {
    float xi = xrow[i];
#pragma unroll
    for (int f = 0; f < EDGE_F; ++f) {
      float m = efr[f] * xi;
      const float* wr = &Wl[(f * IN_F + i) * OUT_F];
#pragma unroll
      for (int o = 0; o < OUT_F; ++o) acc[o] = fmaf(m, wr[o], acc[o]);
    }
  }
  if (valid) {
    float* dp = agg + (size_t)d * OUT_F;
#pragma unroll
    for (int o = 0; o < OUT_F; ++o) atomicAdd(dp + o, acc[o]);
  }
}

// ---------------- BN ----------------
__global__ __launch_bounds__(256) void bn_stats_kernel(
    const float* __restrict__ h, float* __restrict__ stats, int total) {
  int t = blockIdx.x * blockDim.x + threadIdx.x;
  int stride = gridDim.x * blockDim.x;
  float s = 0.f, s2 = 0.f;
  for (int idx = t; idx < total; idx += stride) {
    float v = h[idx];
    s += v;
    s2 = fmaf(v, v, s2);
  }
  __shared__ float ls[256], ls2[256];
  ls[threadIdx.x] = s;
  ls2[threadIdx.x] = s2;
  __syncthreads();
  if (threadIdx.x < 32) {
    float a = ls[threadIdx.x], a2 = ls2[threadIdx.x];
    for (int j = 32 + threadIdx.x; j < 256; j += 32) { a += ls[j]; a2 += ls2[j]; }
    atomicAdd(&stats[threadIdx.x], a);
    atomicAdd(&stats[32 + threadIdx.x], a2);
  }
}

__global__ __launch_bounds__(256) void bn_apply_kernel(
    float* __restrict__ h, const float* __restrict__ stats,
    const float* __restrict__ gamma, const float* __restrict__ beta,
    int total, float invN) {
  int t = blockIdx.x * blockDim.x + threadIdx.x;
  int i4 = t * 4;
  if (i4 >= total) return;
  float4 v = *(const float4*)(h + i4);
  float r[4] = {v.x, v.y, v.z, v.w};
  int o0 = i4 & 31;
#pragma unroll
  for (int j = 0; j < 4; ++j) {
    int o = o0 + j;
    float m = stats[o] * invN;
    float var = fmaf(-m, m, stats[32 + o] * invN);
    float sc = rsqrtf(var + BN_EPS) * gamma[o];
    float val = (r[j] - m) * sc + beta[o];
    r[j] = val >= 0.f ? val : SLOPE * val;
  }
  *(float4*)(h + i4) = make_float4(r[0], r[1], r[2], r[3]);
}

extern "C" void kernel_launch(void* const* d_in, const int* in_sizes, int n_in,
                              void* d_out, int out_size, void* d_ws, size_t ws_size,
                              hipStream_t stream) {
  const float* x     = (const float*)d_in[0];
  const float* ef    = (const float*)d_in[1];
  const float* W     = (const float*)d_in[2];
  const float* b     = (const float*)d_in[3];
  const float* root  = (const float*)d_in[4];
  const float* bias  = (const float*)d_in[5];
  const float* gamma = (const float*)d_in[6];
  const float* beta  = (const float*)d_in[7];
  const int*   ei    = (const int*)d_in[8];

  int N = in_sizes[0] / IN_F;
  int E = in_sizes[1] / EDGE_F;
  int total = N * OUT_F;
  int nb = (N + 255) / 256;  // scan blocks (must be <= 512)

  float* out = (float*)d_out;
  char* wsb = (char*)d_ws;

  size_t off = 0;
  auto alloc = [&](size_t bytes) { size_t o = off; off = (off + bytes + 1023) & ~(size_t)1023; return o; };
  float*  stats  = (float*)(wsb + alloc(256));
  half_t* BtG    = (half_t*)(wsb + alloc(BCOLS * 32 * sizeof(half_t)));
  int*    cnt    = (int*)(wsb + alloc((size_t)N * 4));
  int*    rp     = (int*)(wsb + alloc((size_t)(N + 1) * 4));
  int*    cursor = (int*)(wsb + alloc((size_t)N * 4));
  int*    bsum   = (int*)(wsb + alloc((size_t)nb * 4));
  int*    bcur   = (int*)(wsb + alloc((size_t)nb * 4));
  int*    permd  = (int*)(wsb + alloc((size_t)E * 4));
  half_t* msg    = (half_t*)(wsb + alloc((size_t)E * 32 * sizeof(half_t)));
  half_t* Y      = (half_t*)(wsb + alloc((size_t)N * 544 * sizeof(half_t)));
  size_t need = off;

  if (ws_size >= need && nb <= 512) {
    hipMemsetAsync(stats, 0, 256, stream);
    hipMemsetAsync(cnt, 0, (size_t)N * 4, stream);
    prep_bt_kernel<<<(BCOLS * 32 + 255) / 256, 256, 0, stream>>>(W, b, root, BtG);
    histd_kernel<<<(E + 255) / 256, 256, 0, stream>>>(ei, cnt, E);
    scan_a_kernel<<<nb, 256, 0, stream>>>(cnt, rp, bsum, N);
    scan_b_kernel<<<1, 512, 0, stream>>>(bsum, bcur, nb);
    scan_c_kernel<<<nb, 256, 0, stream>>>(rp, cursor, bcur, N, E);
    scatterd_kernel<<<(E + 255) / 256, 256, 0, stream>>>(ei, cursor, permd, E);
    gemm_y_mfma_kernel<<<(N + 63) / 64, 256, 0, stream>>>(x, BtG, bias, Y, out, N);
    edge_msg_kernel<<<(E + 31) / 32, 256, 0, stream>>>(Y, ef, ei, msg, E);
    node_agg_kernel<<<(N + 31) / 32, 256, 0, stream>>>(msg, rp, permd, out, N);
  } else {
    hipMemsetAsync(stats, 0, 256, stream);
    node_root_kernel<<<(N + 255) / 256, 256, 0, stream>>>(x, root, bias, out, N);
    edge_kernel<<<(E + 255) / 256, 256, 0, stream>>>(x, ef, W, b, ei, out, E);
  }
  bn_stats_kernel<<<1024, 256, 0, stream>>>(out, stats, total);
  bn_apply_kernel<<<(total / 4 + 255) / 256, 256, 0, stream>>>(out, stats, gamma, beta, total, 1.0f / (float)N);
}

// Round 10
// 214.571 us; speedup vs baseline: 1.1289x; 1.0361x over previous
//
#include <hip/hip_runtime.h>

#define IN_F 32
#define OUT_F 32
#define EDGE_F 16
#define BN_EPS 1e-5f
#define SLOPE 0.01f

typedef _Float16 half_t;
typedef __attribute__((ext_vector_type(4))) _Float16 h4;
typedef __attribute__((ext_vector_type(8))) _Float16 f16x8;
typedef __attribute__((ext_vector_type(4))) float f32x4;

#define BCOLS 544        // [W: f*32+o (512) | xb: 512+o (32)]
#define YSTRIDE 552      // fp16 elems per LDS Y row (544 + 8 pad -> 1104B, spreads banks)

// ---------------- P0: build Bt[col][k] fp16; zero cnt32 + stats ----------------
__global__ __launch_bounds__(256) void prep_bt_kernel(
    const float* __restrict__ W, const float* __restrict__ b,
    half_t* __restrict__ BtG, int* __restrict__ cnt32,
    float* __restrict__ stats, int NB) {
  int idx = blockIdx.x * 256 + threadIdx.x;
  if (idx < NB) cnt32[idx] = 0;
  if (idx < 64) stats[idx] = 0.f;
  if (idx >= BCOLS * 32) return;
  int o = idx & 31;
  int k = (idx >> 5) & 31;
  int fp = idx >> 10;  // 0..16
  float v;
  int col;
  if (fp < 16) { v = W[(size_t)fp * 1024 + k * 32 + o]; col = fp * 32 + o; }
  else         { v = b[k * 32 + o];                     col = 512 + o; }
  BtG[(size_t)col * 32 + k] = (half_t)v;
}

// ---------------- S1: histogram of src>>5 ----------------
__global__ __launch_bounds__(256) void hist32_kernel(
    const int* __restrict__ ei, int* __restrict__ cnt, int E) {
  int e = blockIdx.x * 256 + threadIdx.x;
  if (e < E) atomicAdd(&cnt[ei[e] >> 5], 1);
}

// ---------------- S2: single-block exclusive scan over NB buckets ----------------
__global__ __launch_bounds__(1024) void scan32_kernel(
    const int* __restrict__ cnt, int* __restrict__ rp,
    int* __restrict__ cursor, int NB, int E) {
  __shared__ int lds[1024];
  int t = threadIdx.x;
  int C = (NB + 1023) >> 10;
  int base = t * C;
  int s = 0;
  for (int c = 0; c < C; ++c) { int i = base + c; if (i < NB) s += cnt[i]; }
  lds[t] = s;
  __syncthreads();
  for (int off = 1; off < 1024; off <<= 1) {
    int u = (t >= off) ? lds[t - off] : 0;
    __syncthreads();
    lds[t] += u;
    __syncthreads();
  }
  int running = lds[t] - s;  // exclusive prefix
  for (int c = 0; c < C; ++c) {
    int i = base + c;
    if (i < NB) { rp[i] = running; cursor[i] = running; running += cnt[i]; }
  }
  if (t == 0) rp[NB] = E;
}

// ---------------- S3: ranked scatter -> perm (src-bucket order) ----------------
__global__ __launch_bounds__(256) void scatter32_kernel(
    const int* __restrict__ ei, int* __restrict__ cursor,
    int* __restrict__ perm, int E) {
  int e = blockIdx.x * 256 + threadIdx.x;
  if (e < E) {
    int r = atomicAdd(&cursor[ei[e] >> 5], 1);
    perm[r] = e;
  }
}

// ---------------- FUSED: per-32-node tile: MFMA Y -> LDS, then edges -> atomics ----------------
__global__ __launch_bounds__(256, 4) void fused_kernel(
    const float* __restrict__ x, const half_t* __restrict__ BtG,
    const float* __restrict__ ef, const int* __restrict__ ei,
    const int* __restrict__ perm, const int* __restrict__ rp,
    float* __restrict__ out, int N, int E) {
  __shared__ half_t Yl[32][YSTRIDE];  // 35.3 KB
  __shared__ float msgl[32][36];      // 4.6 KB, per-group transpose bounce

  int b = blockIdx.x;
  int n0 = b * 32;
  int t = threadIdx.x;

  // ---- phase A: Y tile via MFMA. wave w: nodes (w&1)*16.., ct half (w>>1) ----
  int wv = t >> 6, lane = t & 63, lr = lane & 15, kg = lane >> 4;
  int nh = wv & 1, ch = wv >> 1;
  int row = n0 + nh * 16 + lr;

  f16x8 a = (f16x8)(half_t)0.f;
  if (row < N) {
    float4 u0 = *(const float4*)(x + (size_t)row * 32 + kg * 8);
    float4 u1 = *(const float4*)(x + (size_t)row * 32 + kg * 8 + 4);
    a[0] = (half_t)u0.x; a[1] = (half_t)u0.y; a[2] = (half_t)u0.z; a[3] = (half_t)u0.w;
    a[4] = (half_t)u1.x; a[5] = (half_t)u1.y; a[6] = (half_t)u1.z; a[7] = (half_t)u1.w;
  }

  int nl0 = nh * 16 + kg * 4;
  for (int ci = 0; ci < 17; ++ci) {
    int col = (ch * 17 + ci) * 16 + lr;           // 0..543
    f16x8 bf = *(const f16x8*)(BtG + (size_t)col * 32 + kg * 8);  // L2-resident
    f32x4 c = {0.f, 0.f, 0.f, 0.f};
    c = __builtin_amdgcn_mfma_f32_16x16x32_f16(a, bf, c, 0, 0, 0);
    // C/D: col = lane&15, row = kg*4+j (verified mapping from R5-R9 kernels)
    Yl[nl0 + 0][col] = (half_t)c[0];
    Yl[nl0 + 1][col] = (half_t)c[1];
    Yl[nl0 + 2][col] = (half_t)c[2];
    Yl[nl0 + 3][col] = (half_t)c[3];
  }
  __syncthreads();

  // ---- phase B: edges of this bucket. 8 lanes/edge, 32 groups ----
  int grp = t >> 3, oq = t & 7;
  int kb = rp[b], ke = rp[b + 1];
  for (int k = kb + grp; k < ke; k += 32) {
    int e = perm[k];
    int s = ei[e];
    int d = ei[E + e];
    int sl = s - n0;

    const float4* ep4 = (const float4*)(ef + (size_t)e * EDGE_F);
    float4 f0 = ep4[0], f1 = ep4[1], f2 = ep4[2], f3 = ep4[3];
    float efr[16] = {f0.x, f0.y, f0.z, f0.w, f1.x, f1.y, f1.z, f1.w,
                     f2.x, f2.y, f2.z, f2.w, f3.x, f3.y, f3.z, f3.w};

    float acc[4];
    {
      h4 xb = *(const h4*)(&Yl[sl][512 + oq * 4]);
      acc[0] = (float)xb[0]; acc[1] = (float)xb[1];
      acc[2] = (float)xb[2]; acc[3] = (float)xb[3];
    }
#pragma unroll
    for (int f = 0; f < 16; ++f) {
      h4 yv = *(const h4*)(&Yl[sl][f * 32 + oq * 4]);
      acc[0] = fmaf(efr[f], (float)yv[0], acc[0]);
      acc[1] = fmaf(efr[f], (float)yv[1], acc[1]);
      acc[2] = fmaf(efr[f], (float)yv[2], acc[2]);
      acc[3] = fmaf(efr[f], (float)yv[3], acc[3]);
    }

    // transpose bounce so each atomic instr covers one 32B sector of dst row
    msgl[grp][oq * 4 + 0] = acc[0];
    msgl[grp][oq * 4 + 1] = acc[1];
    msgl[grp][oq * 4 + 2] = acc[2];
    msgl[grp][oq * 4 + 3] = acc[3];
    asm volatile("s_waitcnt lgkmcnt(0)" ::: "memory");
    float* dp = out + (size_t)d * OUT_F;
    atomicAdd(dp + 0 * 8 + oq, msgl[grp][0 * 8 + oq]);
    atomicAdd(dp + 1 * 8 + oq, msgl[grp][1 * 8 + oq]);
    atomicAdd(dp + 2 * 8 + oq, msgl[grp][2 * 8 + oq]);
    atomicAdd(dp + 3 * 8 + oq, msgl[grp][3 * 8 + oq]);
  }
}

// ---------------- BN stats fused with h0 add: h = agg + x@root + bias ----------------
__global__ __launch_bounds__(256) void bn_stats_fused_kernel(
    const float* __restrict__ x, const float* __restrict__ root,
    const float* __restrict__ bias, float* __restrict__ h,
    float* __restrict__ stats, int N) {
  __shared__ float rl[1024];
  __shared__ float bl[32];
  __shared__ float ls[32], ls2[32];
  int t = threadIdx.x;
  for (int i = t; i < 1024; i += 256) rl[i] = root[i];
  if (t < 32) { bl[t] = bias[t]; ls[t] = 0.f; ls2[t] = 0.f; }
  __syncthreads();

  int o0 = (t & 7) * 4;
  float ts[4] = {0.f, 0.f, 0.f, 0.f};
  float tq[4] = {0.f, 0.f, 0.f, 0.f};
  int stride = gridDim.x * 256;
  for (int g = blockIdx.x * 256 + t; g < N * 8; g += stride) {
    int n = g >> 3;
    float4 a4 = *(const float4*)(h + (size_t)n * 32 + o0);
    float hv[4] = {bl[o0 + 0] + a4.x, bl[o0 + 1] + a4.y,
                   bl[o0 + 2] + a4.z, bl[o0 + 3] + a4.w};
    const float4* xr = (const float4*)(x + (size_t)n * 32);
#pragma unroll
    for (int q = 0; q < 8; ++q) {
      float4 xv = xr[q];
#pragma unroll
      for (int j = 0; j < 4; ++j) {
        hv[j] = fmaf(xv.x, rl[(q * 4 + 0) * 32 + o0 + j], hv[j]);
        hv[j] = fmaf(xv.y, rl[(q * 4 + 1) * 32 + o0 + j], hv[j]);
        hv[j] = fmaf(xv.z, rl[(q * 4 + 2) * 32 + o0 + j], hv[j]);
        hv[j] = fmaf(xv.w, rl[(q * 4 + 3) * 32 + o0 + j], hv[j]);
      }
    }
    *(float4*)(h + (size_t)n * 32 + o0) = make_float4(hv[0], hv[1], hv[2], hv[3]);
#pragma unroll
    for (int j = 0; j < 4; ++j) { ts[j] += hv[j]; tq[j] = fmaf(hv[j], hv[j], tq[j]); }
  }
#pragma unroll
  for (int j = 0; j < 4; ++j) {
    atomicAdd(&ls[o0 + j], ts[j]);
    atomicAdd(&ls2[o0 + j], tq[j]);
  }
  __syncthreads();
  if (t < 32) {
    atomicAdd(&stats[t], ls[t]);
    atomicAdd(&stats[32 + t], ls2[t]);
  }
}

// ---------------- K4: normalize + affine + LeakyReLU ----------------
__global__ __launch_bounds__(256) void bn_apply_kernel(
    float* __restrict__ h, const float* __restrict__ stats,
    const float* __restrict__ gamma, const float* __restrict__ beta,
    int total, float invN) {
  int t = blockIdx.x * blockDim.x + threadIdx.x;
  int i4 = t * 4;
  if (i4 >= total) return;
  float4 v = *(const float4*)(h + i4);
  float r[4] = {v.x, v.y, v.z, v.w};
  int o0 = i4 & 31;
#pragma unroll
  for (int j = 0; j < 4; ++j) {
    int o = o0 + j;
    float m = stats[o] * invN;
    float var = fmaf(-m, m, stats[32 + o] * invN);
    float sc = rsqrtf(var + BN_EPS) * gamma[o];
    float val = (r[j] - m) * sc + beta[o];
    r[j] = val >= 0.f ? val : SLOPE * val;
  }
  *(float4*)(h + i4) = make_float4(r[0], r[1], r[2], r[3]);
}

// ---------------- Fallback path (tiny ws): round-1 kernels ----------------
__global__ __launch_bounds__(256) void node_root_kernel(
    const float* __restrict__ x, const float* __restrict__ root,
    const float* __restrict__ bias, float* __restrict__ agg, int N) {
  __shared__ float rl[IN_F * OUT_F];
  __shared__ float bl[OUT_F];
  for (int t = threadIdx.x; t < IN_F * OUT_F; t += blockDim.x) rl[t] = root[t];
  if (threadIdx.x < OUT_F) bl[threadIdx.x] = bias[threadIdx.x];
  __syncthreads();
  int n = blockIdx.x * blockDim.x + threadIdx.x;
  bool valid = (n < N);
  int nu = valid ? n : 0;
  float xr[IN_F];
  const float4* xp = (const float4*)(x + (size_t)nu * IN_F);
#pragma unroll
  for (int q = 0; q < IN_F / 4; ++q) {
    float4 v = xp[q];
    xr[q * 4 + 0] = v.x; xr[q * 4 + 1] = v.y; xr[q * 4 + 2] = v.z; xr[q * 4 + 3] = v.w;
  }
  float acc[OUT_F];
#pragma unroll
  for (int o = 0; o < OUT_F; ++o) acc[o] = bl[o];
#pragma unroll
  for (int i = 0; i < IN_F; ++i) {
    float xi = xr[i];
#pragma unroll
    for (int o = 0; o < OUT_F; ++o) acc[o] = fmaf(xi, rl[i * OUT_F + o], acc[o]);
  }
  if (valid) {
    float4* op = (float4*)(agg + (size_t)n * OUT_F);
#pragma unroll
    for (int q = 0; q < OUT_F / 4; ++q)
      op[q] = make_float4(acc[q * 4 + 0], acc[q * 4 + 1], acc[q * 4 + 2], acc[q * 4 + 3]);
  }
}

__global__ __launch_bounds__(256) void edge_kernel(
    const float* __restrict__ x, const float* __restrict__ ef,
    const float* __restrict__ W, const float* __restrict__ b,
    const int* __restrict__ ei, float* __restrict__ agg, int E) {
  __shared__ float Wl[EDGE_F * IN_F * OUT_F];
  int e = blockIdx.x * blockDim.x + threadIdx.x;
  bool valid = (e < E);
  int eu = valid ? e : 0;
  int s = ei[eu];
  int d = ei[E + eu];
  float efr[EDGE_F];
  {
    const float4* ep = (const float4*)(ef + (size_t)eu * EDGE_F);
#pragma unroll
    for (int q = 0; q < EDGE_F / 4; ++q) {
      float4 v = ep[q];
      efr[q * 4 + 0] = v.x; efr[q * 4 + 1] = v.y;
      efr[q * 4 + 2] = v.z; efr[q * 4 + 3] = v.w;
    }
  }
  const float* xrow = x + (size_t)s * IN_F;
  float acc[OUT_F];
#pragma unroll
  for (int o = 0; o < OUT_F; ++o) acc[o] = 0.f;
  for (int t = threadIdx.x; t < IN_F * OUT_F; t += 256) Wl[t] = b[t];
  __syncthreads();
  for (int i = 0; i < IN_F; ++i) {
    float xi = xrow[i];
    const float* br = &Wl[i * OUT_F];
#pragma unroll
    for (int o = 0; o < OUT_F; ++o) acc[o] = fmaf(xi, br[o], acc[o]);
  }
  __syncthreads();
  for (int t = threadIdx.x; t < EDGE_F * IN_F * OUT_F / 4; t += 256)
    ((float4*)Wl)[t] = ((const float4*)W)[t];
  __syncthreads();
  for (int i = 0; i < IN_F; ++i) {
    float xi = xrow[i];
#pragma unroll
    for (int f = 0; f < EDGE_F; ++f) {
      float m = efr[f] * xi;
      const float* wr = &Wl[(f * IN_F + i) * OUT_F];
#pragma unroll
      for (int o = 0; o < OUT_F; ++o) acc[o] = fmaf(m, wr[o], acc[o]);
    }
  }
  if (valid) {
    float* dp = agg + (size_t)d * OUT_F;
#pragma unroll
    for (int o = 0; o < OUT_F; ++o) atomicAdd(dp + o, acc[o]);
  }
}

__global__ __launch_bounds__(256) void bn_stats_kernel(
    const float* __restrict__ h, float* __restrict__ stats, int total) {
  int t = blockIdx.x * blockDim.x + threadIdx.x;
  int stride = gridDim.x * blockDim.x;
  float s = 0.f, s2 = 0.f;
  for (int idx = t; idx < total; idx += stride) {
    float v = h[idx];
    s += v;
    s2 = fmaf(v, v, s2);
  }
  __shared__ float ls[256], ls2[256];
  ls[threadIdx.x] = s;
  ls2[threadIdx.x] = s2;
  __syncthreads();
  if (threadIdx.x < 32) {
    float a = ls[threadIdx.x], a2 = ls2[threadIdx.x];
    for (int j = 32 + threadIdx.x; j < 256; j += 32) { a += ls[j]; a2 += ls2[j]; }
    atomicAdd(&stats[threadIdx.x], a);
    atomicAdd(&stats[32 + threadIdx.x], a2);
  }
}

extern "C" void kernel_launch(void* const* d_in, const int* in_sizes, int n_in,
                              void* d_out, int out_size, void* d_ws, size_t ws_size,
                              hipStream_t stream) {
  const float* x     = (const float*)d_in[0];
  const float* ef    = (const float*)d_in[1];
  const float* W     = (const float*)d_in[2];
  const float* b     = (const float*)d_in[3];
  const float* root  = (const float*)d_in[4];
  const float* bias  = (const float*)d_in[5];
  const float* gamma = (const float*)d_in[6];
  const float* beta  = (const float*)d_in[7];
  const int*   ei    = (const int*)d_in[8];

  int N = in_sizes[0] / IN_F;
  int E = in_sizes[1] / EDGE_F;
  int total = N * OUT_F;
  int NB = (N + 31) / 32;

  float* out = (float*)d_out;
  char* wsb = (char*)d_ws;

  size_t off = 0;
  auto alloc = [&](size_t bytes) { size_t o = off; off = (off + bytes + 255) & ~(size_t)255; return o; };
  float*  stats  = (float*)(wsb + alloc(256));
  half_t* BtG    = (half_t*)(wsb + alloc((size_t)BCOLS * 32 * sizeof(half_t)));
  int*    cnt32  = (int*)(wsb + alloc((size_t)NB * 4));
  int*    rp32   = (int*)(wsb + alloc((size_t)(NB + 1) * 4));
  int*    cur32  = (int*)(wsb + alloc((size_t)NB * 4));
  int*    perm32 = (int*)(wsb + alloc((size_t)E * 4));
  size_t need = off;

  if (ws_size >= need) {
    int pgrid = (BCOLS * 32 + 255) / 256;
    int ngrid = (NB + 255) / 256;
    if (ngrid > pgrid) pgrid = ngrid;
    prep_bt_kernel<<<pgrid, 256, 0, stream>>>(W, b, BtG, cnt32, stats, NB);
    hist32_kernel<<<(E + 255) / 256, 256, 0, stream>>>(ei, cnt32, E);
    scan32_kernel<<<1, 1024, 0, stream>>>(cnt32, rp32, cur32, NB, E);
    scatter32_kernel<<<(E + 255) / 256, 256, 0, stream>>>(ei, cur32, perm32, E);
    hipMemsetAsync(out, 0, (size_t)total * sizeof(float), stream);
    fused_kernel<<<NB, 256, 0, stream>>>(x, BtG, ef, ei, perm32, rp32, out, N, E);
    bn_stats_fused_kernel<<<512, 256, 0, stream>>>(x, root, bias, out, stats, N);
  } else {
    hipMemsetAsync(stats, 0, 256, stream);
    node_root_kernel<<<(N + 255) / 256, 256, 0, stream>>>(x, root, bias, out, N);
    edge_kernel<<<(E + 255) / 256, 256, 0, stream>>>(x, ef, W, b, ei, out, E);
    bn_stats_kernel<<<1024, 256, 0, stream>>>(out, stats, total);
  }
  bn_apply_kernel<<<(total / 4 + 255) / 256, 256, 0, stream>>>(out, stats, gamma, beta, total, 1.0f / (float)N);
}